// Round 1
// baseline (181.294 us; speedup 1.0000x reference)
//
#include <hip/hip_runtime.h>
#include <stdint.h>

// VectorQuantizer on MI355X (gfx950), fp32 exact path.
// N=65536 points, D=64, K=512.
// Pass 1: fused (||w||^2 - 2 x.w) + argmin, x in VGPRs, w via scalar loads
//         (wave-uniform addresses), K split into 4 chunks of 128 for occupancy,
//         combined with packed u64 atomicMin (sortable-float | idx).
// Pass 2: gather quantized rows + per-point loss contribution via the identity
//         ||x-q||^2 = ||x||^2 + (||q||^2 - 2 x.q)  (min distance already known).
// Pass 3: reduce loss partials.

#define N_PTS 65536
#define DDIM 64
#define KCODES 512
#define NCHUNK 4
#define KCHUNK 128  // KCODES / NCHUNK

// ws byte layout:
//   wT    : K*D floats  = 131072 B   @ 0
//   wsq   : K floats    = 2048 B     @ 131072
//   xsq   : N floats    = 262144 B   @ 133120
//   lossc : N floats    = 262144 B   @ 395264
//   minkey: N u64       = 524288 B   @ 657408  (8-aligned)
// total ~1.13 MB

__global__ void vq_prep(const float* __restrict__ w, float* __restrict__ wT,
                        float* __restrict__ wsq,
                        unsigned long long* __restrict__ minkey,
                        float* __restrict__ loss_out) {
  int g = blockIdx.x * 256 + threadIdx.x;  // 128 blocks -> 32768 threads = D*K
  // transpose: w is [D][K] row-major; wT is [K][D]
  int d = g >> 9;          // /512
  int k = g & 511;
  wT[k * DDIM + d] = w[g];  // coalesced read, small scatter write (128 KB total)
  // init argmin keys (ws is poisoned 0xAA before every launch)
  minkey[2 * g] = ~0ull;
  minkey[2 * g + 1] = ~0ull;
  // per-code squared norms (read original w, coalesced across k)
  if (g < KCODES) {
    float s = 0.f;
    for (int dd = 0; dd < DDIM; ++dd) {
      float t = w[dd * KCODES + g];
      s = fmaf(t, t, s);
    }
    wsq[g] = s;
  }
  if (g == 0) *loss_out = 0.f;  // d_out is poisoned too
}

__global__ __launch_bounds__(256, 4)
void vq_pass1(const float* __restrict__ x_in, const float* __restrict__ wT,
              const float* __restrict__ wsq,
              unsigned long long* __restrict__ minkey,
              float* __restrict__ xsq_out) {
  // chunk must be derived from blockIdx only so w addresses are provably
  // wave-uniform -> scalar loads (s_load) -> FMA reads 1 SGPR + 1 VGPR.
  const int chunk = blockIdx.x >> 8;                           // 0..3, uniform
  const int n = ((blockIdx.x & 255) << 8) | threadIdx.x;       // point id

  float x[DDIM];
  const float4* xp = (const float4*)(x_in + (size_t)n * DDIM);
#pragma unroll
  for (int i = 0; i < DDIM / 4; ++i) {
    float4 v = xp[i];
    x[4 * i + 0] = v.x; x[4 * i + 1] = v.y;
    x[4 * i + 2] = v.z; x[4 * i + 3] = v.w;
  }

  if (chunk == 0) {
    float s = 0.f;
#pragma unroll
    for (int d = 0; d < DDIM; ++d) s = fmaf(x[d], x[d], s);
    xsq_out[n] = s;
  }

  const int k0 = chunk * KCHUNK;
  float best = 3.0e38f;
  int bidx = 0;

#pragma unroll 1
  for (int g = 0; g < KCHUNK / 8; ++g) {
    const float* __restrict__ wb = wT + (size_t)(k0 + g * 8) * DDIM;
    float acc[8] = {0.f, 0.f, 0.f, 0.f, 0.f, 0.f, 0.f, 0.f};
#pragma unroll
    for (int d = 0; d < DDIM; ++d) {
#pragma unroll
      for (int c = 0; c < 8; ++c) {
        acc[c] = fmaf(wb[c * DDIM + d], x[d], acc[c]);  // s_load * vgpr
      }
    }
#pragma unroll
    for (int c = 0; c < 8; ++c) {
      int ki = k0 + g * 8 + c;
      float dist = fmaf(acc[c], -2.0f, wsq[ki]);
      if (dist < best) { best = dist; bidx = ki; }  // strict < : first-min wins
    }
  }

  // sortable-float transform (monotone), pack with idx in low bits so exact
  // ties resolve to the lowest index (matches argmin semantics).
  unsigned int ub = __float_as_uint(best);
  ub = (ub & 0x80000000u) ? ~ub : (ub | 0x80000000u);
  unsigned long long key =
      ((unsigned long long)ub << 32) | (unsigned long long)(unsigned int)bidx;
  atomicMin(&minkey[n], key);
}

__global__ void vq_pass2(const float* __restrict__ wT,
                         const unsigned long long* __restrict__ minkey,
                         const float* __restrict__ xsq,
                         float* __restrict__ out_q,
                         float* __restrict__ out_idx,
                         float* __restrict__ lossc) {
  int g = blockIdx.x * 256 + threadIdx.x;  // 16384 blocks over N*D
  int n = g >> 6;
  int d = g & 63;
  unsigned long long key = minkey[n];  // wave-uniform (wave = one point)
  unsigned int idx = (unsigned int)(key & 0xFFFFFFFFull);
  out_q[g] = wT[(size_t)idx * DDIM + d];  // coalesced 256B row gather
  if (d == 0) {
    out_idx[n] = (float)idx;
    unsigned int ub = (unsigned int)(key >> 32);
    unsigned int fb = (ub & 0x80000000u) ? (ub & 0x7FFFFFFFu) : ~ub;
    float dist = __uint_as_float(fb);            // ||q||^2 - 2 x.q
    float c = dist + xsq[n];                     // = ||x - q||^2
    lossc[n] = c * (1.25f / 4194304.0f);         // pre-scaled contribution
  }
}

__global__ void vq_pass3(const float* __restrict__ lossc,
                         float* __restrict__ loss_out) {
  __shared__ float sm[256];
  int t = threadIdx.x;
  float s = 0.f;
  for (int i = blockIdx.x * 256 + t; i < N_PTS; i += 64 * 256) s += lossc[i];
  sm[t] = s;
  __syncthreads();
  for (int off = 128; off > 0; off >>= 1) {
    if (t < off) sm[t] += sm[t + off];
    __syncthreads();
  }
  if (t == 0) atomicAdd(loss_out, sm[0]);
}

extern "C" void kernel_launch(void* const* d_in, const int* in_sizes, int n_in,
                              void* d_out, int out_size, void* d_ws, size_t ws_size,
                              hipStream_t stream) {
  const float* x = (const float*)d_in[0];  // (64,32,32,64) fp32
  const float* w = (const float*)d_in[1];  // (64,512) fp32

  char* ws = (char*)d_ws;
  float* wT = (float*)(ws);
  float* wsq = (float*)(ws + 131072);
  float* xsq = (float*)(ws + 133120);
  float* lossc = (float*)(ws + 395264);
  unsigned long long* minkey = (unsigned long long*)(ws + 657408);

  float* out_q = (float*)d_out;                 // 4194304 floats
  float* out_idx = out_q + 4194304;             // 65536 floats (indices as f32)
  float* loss_out = out_q + 4259840;            // 1 float

  vq_prep<<<128, 256, 0, stream>>>(w, wT, wsq, minkey, loss_out);
  vq_pass1<<<256 * NCHUNK, 256, 0, stream>>>(x, wT, wsq, minkey, xsq);
  vq_pass2<<<16384, 256, 0, stream>>>(wT, minkey, xsq, out_q, out_idx, lossc);
  vq_pass3<<<64, 256, 0, stream>>>(lossc, loss_out);
}